// Round 14
// baseline (208.089 us; speedup 1.0000x reference)
//
#include <hip/hip_runtime.h>
#include <hip/hip_bf16.h>

typedef unsigned short u16;
typedef __attribute__((ext_vector_type(8))) short bf16x8;
typedef __attribute__((ext_vector_type(4))) float f32x4;

#define AS1 __attribute__((address_space(1)))
#define AS3 __attribute__((address_space(3)))

// ---- constants for this problem ----
#define Bx 8
#define Tt 2048
#define Dd 1024
#define Nn 256
#define Mm (Bx*Tt)          // 16384
#define CHAINS (Bx*Nn)      // 2048
#define NCH 32
#define TC 64               // T / NCH
#define NCOMB 1792          // 768 (abc) + 1024 (d)

#define WS_NEED 105644032u

#define CVT_BLOCKS (Mm*Dd/4/256)   // 16384
#define PACK_BLOCKS (32*32*5)      // 5120

#define VMCNT0 asm volatile("s_waitcnt vmcnt(0)" ::: "memory")
#define BARR   __builtin_amdgcn_s_barrier()
#define SCHEDB __builtin_amdgcn_sched_barrier(0)

__device__ __forceinline__ u16 f2bf(float f) {
  union { float f; unsigned u; } v; v.f = f;
  unsigned u = v.u;
  u += 0x7fffu + ((u >> 16) & 1u);   // RNE
  return (u16)(u >> 16);
}

__device__ __forceinline__ float bf2f(u16 h) {
  union { unsigned u; float f; } v; v.u = ((unsigned)h) << 16;
  return v.f;
}

__device__ __forceinline__ void gload_lds16(const void* g, void* l) {
  __builtin_amdgcn_global_load_lds((AS1 void*)(g), (AS3 void*)(l), 16, 0, 0);
}

// ---------------- fused prep: x fp32->bf16 + weight pack ----------------
__global__ void prep_kernel(const float* __restrict__ x, u16* __restrict__ xb,
                            const float* __restrict__ Wa, const float* __restrict__ Wb,
                            const float* __restrict__ Wc, const float* __restrict__ Wd,
                            const float* __restrict__ Wy,
                            u16* __restrict__ Wcomb, u16* __restrict__ Wyt) {
  const int bid = blockIdx.x;
  if (bid < CVT_BLOCKS) {
    int i = bid * blockDim.x + threadIdx.x;
    float4 v = ((const float4*)x)[i];
    unsigned lo = (unsigned)f2bf(v.x) | ((unsigned)f2bf(v.y) << 16);
    unsigned hi = (unsigned)f2bf(v.z) | ((unsigned)f2bf(v.w) << 16);
    ((uint2*)xb)[i] = make_uint2(lo, hi);
    return;
  }
  __shared__ float tile[32][33];
  const int pid = bid - CVT_BLOCKS;
  const int z = pid >> 10;          // /1024
  const int rem = pid & 1023;
  const int bx = rem & 31, by = rem >> 5;
  const float* src; u16* dst; int R, C, dld;
  if (z < 3)       { src = (z==0?Wa:(z==1?Wb:Wc)); dst = Wcomb + (size_t)z*256*1024; R=1024; C=256;  dld=1024; }
  else if (z == 3) { src = Wd; dst = Wcomb + (size_t)768*1024; R=1024; C=1024; dld=1024; }
  else             { src = Wy; dst = Wyt; R=256;  C=1024; dld=256;  }
  int c0 = bx * 32, r0 = by * 32;
  if (c0 >= C || r0 >= R) return;
  int tx = threadIdx.x & 31, ty = threadIdx.x >> 5;   // 32x8
  #pragma unroll
  for (int i = 0; i < 32; i += 8)
    tile[ty + i][tx] = src[(size_t)(r0 + ty + i)*C + (c0 + tx)];
  __syncthreads();
  #pragma unroll
  for (int i = 0; i < 32; i += 8) {
    int c = c0 + ty + i, r = r0 + tx;
    dst[(size_t)c*dld + r] = f2bf(tile[tx][ty + i]);
  }
}

// ---------------- GEMM: C[M,*] = A[M,K] * Bt[*,K]^T, bf16 in, fp32 acc ----
// T3-min double-buffer recipe (m230/m248v2) on the r9-proven 128x128/4-wave
// fragment mapping:
//   prologue: STAGE(buf0, 0); vmcnt(0); barrier;
//   iter t:   STAGE(buf[t+1 & 1], t+1)   <- issued FIRST (top of iter)
//             ds_read frags from buf[t&1]; MFMA (setprio);
//             vmcnt(0); s_barrier;        <- single drain per tile, at END:
//                                            loads had the whole compute
//                                            phase to land.
// 2 x 32KB LDS, 2 blocks/CU (reg cap 128 via launch_bounds(256,4)).
// T2 slot-XOR swizzle both-sides; T1 XCD-chunked swizzle, n-fastest.
// EPI 0: coln<768 -> abc (bf16) sigmoid/+bias/tanh; else d -> bf16 dtmp.
// EPI 2: outO = acc + b0[col] + dtmp[row,col]
template<int EPI>
__global__ __launch_bounds__(256, 4) void gemm_bt_kernel(
    const u16* __restrict__ A, const u16* __restrict__ Bt, int K, int gx,
    u16* __restrict__ outA, float* __restrict__ outO, u16* __restrict__ dtmp,
    const float* __restrict__ b0, const float* __restrict__ b1,
    const float* __restrict__ b2, const float* __restrict__ b3) {
  __shared__ u16 ldsA[2*128*64];   // 2 x 16 KiB
  __shared__ u16 ldsB[2*128*64];   // 2 x 16 KiB
  const int tid = threadIdx.x;
  const int lane = tid & 63, wid = tid >> 6;
  const int wr = wid >> 1, wc = wid & 1;

  // XCD-chunked bijective swizzle (gridDim.x % 8 == 0), n-fastest in chunk
  const int h = blockIdx.x;
  const int id = (h & 7) * (gridDim.x >> 3) + (h >> 3);
  const int mt = id / gx, nt = id % gx;
  const int m0 = mt * 128, n0 = nt * 128;
  const int NT = K >> 6;

  f32x4 acc[4][4] = {};

  // staging: lane l covers (row = g*8 + (l>>3), 16B slot = (l&7)^(row&7))
  const int srow = lane >> 3;
  const int sq   = (lane & 7) ^ srow;

  auto stage = [&](int b, int t) {
    const int k0 = t << 6;
    #pragma unroll
    for (int i = 0; i < 4; ++i) {
      int g = wid*4 + i;
      int r = g*8 + srow;
      gload_lds16(A + (size_t)(m0 + r)*K + k0 + sq*8, (char*)ldsA + b*16384 + g*1024);
      gload_lds16(Bt + (size_t)(n0 + r)*K + k0 + sq*8, (char*)ldsB + b*16384 + g*1024);
    }
  };

  // ds_read swizzle params
  const int kq  = lane >> 4;        // k-quarter within 32-wide half
  const int swz = lane & 7;         // == row&7 for all fragment rows
  const int arow = wr*64 + (lane & 15);
  const int brow = wc*64 + (lane & 15);

  // prologue: tile 0 into buf 0, full drain
  stage(0, 0);
  VMCNT0;
  BARR; SCHEDB;

  for (int t = 0; t < NT; ++t) {
    const int cur = t & 1;
    const int cb  = cur * 8192;     // u16 offset of current buffer

    // issue next-tile loads FIRST -> they land during this tile's compute
    if (t + 1 < NT) stage(cur ^ 1, t + 1);
    SCHEDB;                          // pin stage issue above the ds_reads

    #pragma unroll
    for (int kk = 0; kk < 2; ++kk) {
      const int q = ((kk*4 + kq) ^ swz) * 8;   // swizzled element offset
      bf16x8 af[4], bfr[4];
      #pragma unroll
      for (int mi = 0; mi < 4; ++mi)
        af[mi]  = *(const bf16x8*)&ldsA[cb + (arow + mi*16)*64 + q];
      #pragma unroll
      for (int ni = 0; ni < 4; ++ni)
        bfr[ni] = *(const bf16x8*)&ldsB[cb + (brow + ni*16)*64 + q];
      __builtin_amdgcn_s_setprio(1);
      #pragma unroll
      for (int mi = 0; mi < 4; ++mi)
        #pragma unroll
        for (int ni = 0; ni < 4; ++ni)
          acc[mi][ni] = __builtin_amdgcn_mfma_f32_16x16x32_bf16(af[mi], bfr[ni], acc[mi][ni], 0, 0, 0);
      __builtin_amdgcn_s_setprio(0);
    }

    VMCNT0;        // residual wait only: loads have been in flight all iter
    BARR; SCHEDB;  // all waves synced: buf[cur] free for overwrite next iter
  }

  // epilogue: C/D layout col=lane&15, row=(lane>>4)*4+r  [m89-verified]
  const int crow = m0 + wr*64 + (lane >> 4)*4;
  const int ccol = wc*64 + (lane & 15);
  #pragma unroll
  for (int mi = 0; mi < 4; ++mi) {
    #pragma unroll
    for (int ni = 0; ni < 4; ++ni) {
      int coln = n0 + ccol + ni*16;
      #pragma unroll
      for (int r = 0; r < 4; ++r) {
        int row = crow + mi*16 + r;
        float v = acc[mi][ni][r];
        if (EPI == 0) {
          if (coln < 768) {
            int seg = coln >> 8, cn = coln & 255;
            if (seg == 0)      v = 1.f / (1.f + __expf(-(v + b0[cn])));
            else if (seg == 1) v = v + b1[cn];
            else               v = tanhf(v + b2[cn]);
            outA[(size_t)row*768 + coln] = f2bf(v);
          } else {
            int col = coln - 768;
            if (dtmp) dtmp[(size_t)row*1024 + col] = f2bf(v + b3[col]);
            else      outO[(size_t)row*1024 + col] = v + b3[col];
          }
        } else {
          const size_t o = (size_t)row*1024 + coln;
          if (dtmp) outO[o] = v + b0[coln] + bf2f(dtmp[o]);
          else      outO[o] = outO[o] + v + b0[coln];
        }
      }
    }
  }
}

// ---------------- scan: s_t = a*s + (1-a)*b ; cs = c*s ----------------
// abc layout: (m, 768) BF16, cols [0,256)=a (post-sigmoid), [256,512)=b,
// [512,768)=c (post-tanh)
__global__ void scanA_kernel(const u16* __restrict__ abc,
                             float* __restrict__ Asum, float* __restrict__ Usum) {
  int idx = blockIdx.x * blockDim.x + threadIdx.x;    // chunk*2048 + chain
  int chain = idx & (CHAINS - 1);
  int ch = idx >> 11;
  int bb = chain >> 8, n = chain & 255;
  const u16* base = abc + (size_t)(bb*Tt + ch*TC) * 768;
  float A = 1.f, U = 0.f;
  for (int t = 0; t < TC; ++t) {
    float a = bf2f(base[(size_t)t*768 + n]);
    float b = bf2f(base[(size_t)t*768 + 256 + n]);
    U = a*U + (1.f - a)*b;
    A *= a;
  }
  Asum[idx] = A; Usum[idx] = U;
}

__global__ void scanB_kernel(const float* __restrict__ Asum, const float* __restrict__ Usum,
                             float* __restrict__ Spre) {
  int chain = blockIdx.x * blockDim.x + threadIdx.x;  // 0..2047
  float s = 0.f;
  for (int ch = 0; ch < NCH; ++ch) {
    int i = (ch << 11) + chain;
    Spre[i] = s;
    s = Asum[i]*s + Usum[i];
  }
}

__global__ void scanC_kernel(const u16* __restrict__ abc, const float* __restrict__ Spre,
                             u16* __restrict__ cs) {
  int idx = blockIdx.x * blockDim.x + threadIdx.x;
  int chain = idx & (CHAINS - 1);
  int ch = idx >> 11;
  int bb = chain >> 8, n = chain & 255;
  const u16* base = abc + (size_t)(bb*Tt + ch*TC) * 768;
  u16* csb = cs + (size_t)(bb*Tt + ch*TC) * 256 + n;
  float s = Spre[idx];
  for (int t = 0; t < TC; ++t) {
    float a = bf2f(base[(size_t)t*768 + n]);
    float b = bf2f(base[(size_t)t*768 + 256 + n]);
    float c = bf2f(base[(size_t)t*768 + 512 + n]);
    s = a*s + (1.f - a)*b;
    csb[(size_t)t*256] = f2bf(c*s);
  }
}

extern "C" void kernel_launch(void* const* d_in, const int* in_sizes, int n_in,
                              void* d_out, int out_size, void* d_ws, size_t ws_size,
                              hipStream_t stream) {
  const float* x  = (const float*)d_in[0];
  const float* Wa = (const float*)d_in[1];
  const float* ba = (const float*)d_in[2];
  const float* Wb = (const float*)d_in[3];
  const float* bb = (const float*)d_in[4];
  const float* Wc = (const float*)d_in[5];
  const float* bc = (const float*)d_in[6];
  const float* Wd = (const float*)d_in[7];
  const float* bd = (const float*)d_in[8];
  const float* Wy = (const float*)d_in[9];
  const float* by = (const float*)d_in[10];
  float* out = (float*)d_out;
  char* ws = (char*)d_ws;

  // workspace layout (bytes)
  u16*  xb    = (u16*) (ws + 0);          // 33,554,432
  u16*  Wcomb = (u16*) (ws + 33554432);   //  3,670,016
  u16*  Wyt   = (u16*) (ws + 37224448);   //    524,288
  u16*  abcb  = (u16*) (ws + 37748736);   // 25,165,824 (bf16 abc)
  u16*  cs    = (u16*) (ws + 62914560);   //  8,388,608
  float* Asum = (float*)(ws + 71303168);  //    262,144
  float* Usum = (float*)(ws + 71565312);  //    262,144
  float* Spre = (float*)(ws + 71827456);  //    262,144
  u16*  dtmp  = (ws_size >= WS_NEED) ? (u16*)(ws + 72089600) : nullptr; // 33,554,432

  // 1) fused prep: x->bf16 + weight pack (one launch)
  prep_kernel<<<CVT_BLOCKS + PACK_BLOCKS, 256, 0, stream>>>(
      x, xb, Wa, Wb, Wc, Wd, Wy, Wcomb, Wyt);
  // 2) fused GEMM: abcb = act(x@[Wa|Wb|Wc]+bias) bf16, dtmp = x@Wd + bd (bf16)
  //    grid = (16384/128) * (1792/128) = 128*14 = 1792 (div by 8; 224/14=16)
  gemm_bt_kernel<0><<<1792, 256, 0, stream>>>(
      xb, Wcomb, Dd, NCOMB/128, abcb, out, dtmp, ba, bb, bc, bd);
  // 3) chunked scan
  scanA_kernel<<<CHAINS*NCH/256, 256, 0, stream>>>(abcb, Asum, Usum);
  scanB_kernel<<<CHAINS/256, 256, 0, stream>>>(Asum, Usum, Spre);
  scanC_kernel<<<CHAINS*NCH/256, 256, 0, stream>>>(abcb, Spre, cs);
  // 4) out = cs @ Wy + by + dtmp   grid = 128*8 = 1024 (div by 8; 128/8=16)
  gemm_bt_kernel<2><<<1024, 256, 0, stream>>>(
      cs, Wyt, Nn, Dd/128, nullptr, out, dtmp, by, nullptr, nullptr, nullptr);
}

// Round 15
// 150.565 us; speedup vs baseline: 1.3821x; 1.3821x over previous
//
#include <hip/hip_runtime.h>
#include <hip/hip_bf16.h>

typedef unsigned short u16;
typedef __attribute__((ext_vector_type(8))) short bf16x8;
typedef __attribute__((ext_vector_type(4))) float f32x4;

#define AS1 __attribute__((address_space(1)))
#define AS3 __attribute__((address_space(3)))

// ---- constants for this problem ----
#define Bx 8
#define Tt 2048
#define Dd 1024
#define Nn 256
#define Mm (Bx*Tt)          // 16384
#define CHAINS (Bx*Nn)      // 2048
#define NCH 32
#define TC 64               // T / NCH
#define NCOMB 1792          // 768 (abc) + 1024 (d)

#define WS_NEED 105644032u

#define CVT_BLOCKS (Mm*Dd/8/256)   // 8192 (8 floats per thread)
#define PACK_BLOCKS (32*32*5)      // 5120

__device__ __forceinline__ u16 f2bf(float f) {
  union { float f; unsigned u; } v; v.f = f;
  unsigned u = v.u;
  u += 0x7fffu + ((u >> 16) & 1u);   // RNE
  return (u16)(u >> 16);
}

__device__ __forceinline__ float bf2f(u16 h) {
  union { unsigned u; float f; } v; v.u = ((unsigned)h) << 16;
  return v.f;
}

__device__ __forceinline__ void gload_lds16(const void* g, void* l) {
  __builtin_amdgcn_global_load_lds((AS1 void*)(g), (AS3 void*)(l), 16, 0, 0);
}

// ---------------- fused prep: x fp32->bf16 + weight pack ----------------
// blocks [0, CVT_BLOCKS): convert x (8 floats/thread)
// blocks [CVT_BLOCKS, ...): transpose+convert weights
__global__ void prep_kernel(const float* __restrict__ x, u16* __restrict__ xb,
                            const float* __restrict__ Wa, const float* __restrict__ Wb,
                            const float* __restrict__ Wc, const float* __restrict__ Wd,
                            const float* __restrict__ Wy,
                            u16* __restrict__ Wcomb, u16* __restrict__ Wyt) {
  const int bid = blockIdx.x;
  if (bid < CVT_BLOCKS) {
    int i = bid * blockDim.x + threadIdx.x;
    #pragma unroll
    for (int j = 0; j < 2; ++j) {
      float4 v = ((const float4*)x)[2*i + j];
      unsigned lo = (unsigned)f2bf(v.x) | ((unsigned)f2bf(v.y) << 16);
      unsigned hi = (unsigned)f2bf(v.z) | ((unsigned)f2bf(v.w) << 16);
      ((uint2*)xb)[2*i + j] = make_uint2(lo, hi);
    }
    return;
  }
  __shared__ float tile[32][33];
  const int pid = bid - CVT_BLOCKS;
  const int z = pid >> 10;          // /1024
  const int rem = pid & 1023;
  const int bx = rem & 31, by = rem >> 5;
  const float* src; u16* dst; int R, C, dld;
  if (z < 3)       { src = (z==0?Wa:(z==1?Wb:Wc)); dst = Wcomb + (size_t)z*256*1024; R=1024; C=256;  dld=1024; }
  else if (z == 3) { src = Wd; dst = Wcomb + (size_t)768*1024; R=1024; C=1024; dld=1024; }
  else             { src = Wy; dst = Wyt; R=256;  C=1024; dld=256;  }
  int c0 = bx * 32, r0 = by * 32;
  if (c0 >= C || r0 >= R) return;
  int tx = threadIdx.x & 31, ty = threadIdx.x >> 5;   // 32x8
  #pragma unroll
  for (int i = 0; i < 32; i += 8)
    tile[ty + i][tx] = src[(size_t)(r0 + ty + i)*C + (c0 + tx)];
  __syncthreads();
  #pragma unroll
  for (int i = 0; i < 32; i += 8) {
    int c = c0 + ty + i, r = r0 + tx;
    dst[(size_t)c*dld + r] = f2bf(tile[tx][ty + i]);
  }
}

// ---------------- GEMM: C[M,*] = A[M,K] * Bt[*,K]^T, bf16 in, fp32 acc ----
// ROUND-13 PROVEN CONFIG (131us EPI0, best): BM=256 x BN=128, 8 waves
// (4 wm x 2 wn), per-wave acc[4][4] (64x64 output), BK=64, 48KB single-buffer
// LDS, syncthreads K-loop, T5 setprio around MFMA cluster,
// T2 slot-XOR swizzle both-sides, T1 XCD-chunked swizzle n-fastest.
// (Five pipelining attempts r3/r7/r10/r14 all regressed: short-K problem
// favors 16 waves/CU TLP over intra-block ILP; do not re-attempt blind.)
// EPI 0: coln<768 -> abc (bf16) with sigmoid/+bias/fast-tanh; else d -> bf16
// dtmp. EPI 2: outO = acc + b0[col] + dtmp[row,col]
template<int EPI>
__global__ __launch_bounds__(512, 4) void gemm_bt_kernel(
    const u16* __restrict__ A, const u16* __restrict__ Bt, int K, int gx,
    u16* __restrict__ outA, float* __restrict__ outO, u16* __restrict__ dtmp,
    const float* __restrict__ b0, const float* __restrict__ b1,
    const float* __restrict__ b2, const float* __restrict__ b3) {
  __shared__ u16 ldsA[256*64];   // 32 KiB
  __shared__ u16 ldsB[128*64];   // 16 KiB
  const int tid = threadIdx.x;
  const int lane = tid & 63, wid = tid >> 6;
  const int wm = wid >> 1, wn = wid & 1;

  // XCD-chunked bijective swizzle (gridDim.x % 8 == 0), n-fastest in chunk
  const int h = blockIdx.x;
  const int id = (h & 7) * (gridDim.x >> 3) + (h >> 3);
  const int mt = id / gx, nt = id % gx;
  const int m0 = mt * 256, n0 = nt * 128;

  f32x4 acc[4][4] = {};

  // staging: thread covers (row = u*64 + rl, 16B slot ssl), 512 thr = 64 rows
  const int rl  = tid >> 3;                 // 0..63
  const int ssl = (tid & 7) ^ (rl & 7);     // pre-swizzled source slot

  auto stage = [&](int k0) {
    #pragma unroll
    for (int u = 0; u < 4; ++u)             // A: 256 rows = 4 units
      gload_lds16(A + (size_t)(m0 + u*64 + rl)*K + k0 + ssl*8,
                  ldsA + u*4096 + tid*8);
    #pragma unroll
    for (int u = 0; u < 2; ++u)             // B: 128 rows = 2 units
      gload_lds16(Bt + (size_t)(n0 + u*64 + rl)*K + k0 + ssl*8,
                  ldsB + u*4096 + tid*8);
  };

  // ds_read swizzle params
  const int lr = lane & 15, kq = lane >> 4, sw = lane & 7;
  const int arow = wm*64 + lr;
  const int brow = wn*64 + lr;

  for (int k0 = 0; k0 < K; k0 += 64) {
    stage(k0);
    __syncthreads();
    #pragma unroll
    for (int kk = 0; kk < 2; ++kk) {
      const int q = ((kk*4 + kq) ^ sw) * 8;   // swizzled element offset in row
      bf16x8 af[4], bfr[4];
      #pragma unroll
      for (int mi = 0; mi < 4; ++mi)
        af[mi]  = *(const bf16x8*)&ldsA[(arow + mi*16)*64 + q];
      #pragma unroll
      for (int ni = 0; ni < 4; ++ni)
        bfr[ni] = *(const bf16x8*)&ldsB[(brow + ni*16)*64 + q];
      __builtin_amdgcn_s_setprio(1);
      #pragma unroll
      for (int mi = 0; mi < 4; ++mi)
        #pragma unroll
        for (int ni = 0; ni < 4; ++ni)
          acc[mi][ni] = __builtin_amdgcn_mfma_f32_16x16x32_bf16(af[mi], bfr[ni], acc[mi][ni], 0, 0, 0);
      __builtin_amdgcn_s_setprio(0);
    }
    __syncthreads();
  }

  // epilogue: C/D layout col=lane&15, row=(lane>>4)*4+r  [m89-verified]
  const int crow = m0 + wm*64 + (lane >> 4)*4;
  const int ccol = wn*64 + (lane & 15);
  #pragma unroll
  for (int mi = 0; mi < 4; ++mi) {
    #pragma unroll
    for (int ni = 0; ni < 4; ++ni) {
      int coln = n0 + ccol + ni*16;
      #pragma unroll
      for (int r = 0; r < 4; ++r) {
        int row = crow + mi*16 + r;
        float v = acc[mi][ni][r];
        if (EPI == 0) {
          if (coln < 768) {
            int seg = coln >> 8, cn = coln & 255;
            if (seg == 0)      v = 1.f / (1.f + __expf(-(v + b0[cn])));
            else if (seg == 1) v = v + b1[cn];
            else {             // fast tanh: 1 - 2/(1+e^{2x})
              float e = __expf(2.f*(v + b2[cn]));
              v = 1.f - 2.f/(1.f + e);
            }
            outA[(size_t)row*768 + coln] = f2bf(v);
          } else {
            int col = coln - 768;
            if (dtmp) dtmp[(size_t)row*1024 + col] = f2bf(v + b3[col]);
            else      outO[(size_t)row*1024 + col] = v + b3[col];
          }
        } else {
          const size_t o = (size_t)row*1024 + coln;
          if (dtmp) outO[o] = v + b0[coln] + bf2f(dtmp[o]);
          else      outO[o] = outO[o] + v + b0[coln];
        }
      }
    }
  }
}

// ---------------- scan: s_t = a*s + (1-a)*b ; cs = c*s ----------------
// abc layout: (m, 768) BF16, cols [0,256)=a (post-sigmoid), [256,512)=b,
// [512,768)=c (post-tanh)
__global__ void scanA_kernel(const u16* __restrict__ abc,
                             float* __restrict__ Asum, float* __restrict__ Usum) {
  int idx = blockIdx.x * blockDim.x + threadIdx.x;    // chunk*2048 + chain
  int chain = idx & (CHAINS - 1);
  int ch = idx >> 11;
  int bb = chain >> 8, n = chain & 255;
  const u16* base = abc + (size_t)(bb*Tt + ch*TC) * 768;
  float A = 1.f, U = 0.f;
  for (int t = 0; t < TC; ++t) {
    float a = bf2f(base[(size_t)t*768 + n]);
    float b = bf2f(base[(size_t)t*768 + 256 + n]);
    U = a*U + (1.f - a)*b;
    A *= a;
  }
  Asum[idx] = A; Usum[idx] = U;
}

__global__ void scanB_kernel(const float* __restrict__ Asum, const float* __restrict__ Usum,
                             float* __restrict__ Spre) {
  int chain = blockIdx.x * blockDim.x + threadIdx.x;  // 0..2047
  float s = 0.f;
  for (int ch = 0; ch < NCH; ++ch) {
    int i = (ch << 11) + chain;
    Spre[i] = s;
    s = Asum[i]*s + Usum[i];
  }
}

__global__ void scanC_kernel(const u16* __restrict__ abc, const float* __restrict__ Spre,
                             u16* __restrict__ cs) {
  int idx = blockIdx.x * blockDim.x + threadIdx.x;
  int chain = idx & (CHAINS - 1);
  int ch = idx >> 11;
  int bb = chain >> 8, n = chain & 255;
  const u16* base = abc + (size_t)(bb*Tt + ch*TC) * 768;
  u16* csb = cs + (size_t)(bb*Tt + ch*TC) * 256 + n;
  float s = Spre[idx];
  for (int t = 0; t < TC; ++t) {
    float a = bf2f(base[(size_t)t*768 + n]);
    float b = bf2f(base[(size_t)t*768 + 256 + n]);
    float c = bf2f(base[(size_t)t*768 + 512 + n]);
    s = a*s + (1.f - a)*b;
    csb[(size_t)t*256] = f2bf(c*s);
  }
}

extern "C" void kernel_launch(void* const* d_in, const int* in_sizes, int n_in,
                              void* d_out, int out_size, void* d_ws, size_t ws_size,
                              hipStream_t stream) {
  const float* x  = (const float*)d_in[0];
  const float* Wa = (const float*)d_in[1];
  const float* ba = (const float*)d_in[2];
  const float* Wb = (const float*)d_in[3];
  const float* bb = (const float*)d_in[4];
  const float* Wc = (const float*)d_in[5];
  const float* bc = (const float*)d_in[6];
  const float* Wd = (const float*)d_in[7];
  const float* bd = (const float*)d_in[8];
  const float* Wy = (const float*)d_in[9];
  const float* by = (const float*)d_in[10];
  float* out = (float*)d_out;
  char* ws = (char*)d_ws;

  // workspace layout (bytes)
  u16*  xb    = (u16*) (ws + 0);          // 33,554,432
  u16*  Wcomb = (u16*) (ws + 33554432);   //  3,670,016
  u16*  Wyt   = (u16*) (ws + 37224448);   //    524,288
  u16*  abcb  = (u16*) (ws + 37748736);   // 25,165,824 (bf16 abc)
  u16*  cs    = (u16*) (ws + 62914560);   //  8,388,608
  float* Asum = (float*)(ws + 71303168);  //    262,144
  float* Usum = (float*)(ws + 71565312);  //    262,144
  float* Spre = (float*)(ws + 71827456);  //    262,144
  u16*  dtmp  = (ws_size >= WS_NEED) ? (u16*)(ws + 72089600) : nullptr; // 33,554,432

  // 1) fused prep: x->bf16 + weight pack (one launch)
  prep_kernel<<<CVT_BLOCKS + PACK_BLOCKS, 256, 0, stream>>>(
      x, xb, Wa, Wb, Wc, Wd, Wy, Wcomb, Wyt);
  // 2) fused GEMM: abcb = act(x@[Wa|Wb|Wc]+bias) bf16, dtmp = x@Wd + bd (bf16)
  //    grid = (16384/256) * (1792/128) = 64*14 = 896 (div by 8)
  gemm_bt_kernel<0><<<896, 512, 0, stream>>>(
      xb, Wcomb, Dd, NCOMB/128, abcb, out, dtmp, ba, bb, bc, bd);
  // 3) chunked scan
  scanA_kernel<<<CHAINS*NCH/256, 256, 0, stream>>>(abcb, Asum, Usum);
  scanB_kernel<<<CHAINS/256, 256, 0, stream>>>(Asum, Usum, Spre);
  scanC_kernel<<<CHAINS*NCH/256, 256, 0, stream>>>(abcb, Spre, cs);
  // 4) out = cs @ Wy + by + dtmp   grid = 64*8 = 512 (div by 8)
  gemm_bt_kernel<2><<<512, 512, 0, stream>>>(
      cs, Wyt, Nn, Dd/128, nullptr, out, dtmp, by, nullptr, nullptr, nullptr);
}